// Round 1
// baseline (894.425 us; speedup 1.0000x reference)
//
#include <hip/hip_runtime.h>
#include <cmath>

// SSIM loss, fused: blur(a), blur(b), blur(a^2), blur(b^2), blur(ab) per tile,
// then exact reference SSIM formula, global mean, 1 - mean, summed for 3D+2D parts.

#define WSZ 11
#define HALO 5
#define TX 32
#define TY 32
#define IN_W (TX + WSZ - 1)   // 42
#define IN_H (TY + WSZ - 1)   // 42
#define IMG_W 512
#define IMG_H 512
#define SLICE (IMG_W * IMG_H)

struct G11 { float w[WSZ]; };

__global__ __launch_bounds__(256) void ssim_tile_kernel(
    const float* __restrict__ A, const float* __restrict__ B,
    double* __restrict__ acc, G11 gw)
{
    __shared__ float sA[IN_H][IN_W];
    __shared__ float sB[IN_H][IN_W];
    __shared__ float h1[IN_H][TX];
    __shared__ float h2[IN_H][TX];
    __shared__ float h3[IN_H][TX];
    __shared__ float h4[IN_H][TX];
    __shared__ float h5[IN_H][TX];

    const int tid = threadIdx.x;
    const int x0 = blockIdx.x * TX;
    const int y0 = blockIdx.y * TY;
    const long base = (long)blockIdx.z * SLICE;

    // Stage 1: load input tile with zero padding (matches conv zero-pad).
    for (int p = tid; p < IN_H * IN_W; p += 256) {
        int r = p / IN_W, c = p - r * IN_W;
        int gy = y0 + r - HALO, gx = x0 + c - HALO;
        float va = 0.f, vb = 0.f;
        if (gy >= 0 && gy < IMG_H && gx >= 0 && gx < IMG_W) {
            long off = base + (long)gy * IMG_W + gx;
            va = A[off];
            vb = B[off];
        }
        sA[r][c] = va;
        sB[r][c] = vb;
    }
    __syncthreads();

    // Stage 2: horizontal blur of 5 channels over all IN_H rows.
    for (int p = tid; p < IN_H * TX; p += 256) {
        int r = p >> 5, c = p & 31;
        float s1 = 0.f, s2 = 0.f, s3 = 0.f, s4 = 0.f, s5 = 0.f;
        #pragma unroll
        for (int k = 0; k < WSZ; k++) {
            float g = gw.w[k];
            float va = sA[r][c + k];
            float vb = sB[r][c + k];
            s1 += g * va;
            s2 += g * vb;
            s3 += g * va * va;
            s4 += g * vb * vb;
            s5 += g * va * vb;
        }
        h1[r][c] = s1; h2[r][c] = s2; h3[r][c] = s3; h4[r][c] = s4; h5[r][c] = s5;
    }
    __syncthreads();

    // Stage 3: vertical blur + SSIM formula + local accumulation.
    float localsum = 0.f;
    for (int p = tid; p < TY * TX; p += 256) {
        int r = p >> 5, c = p & 31;
        float m1 = 0.f, m2 = 0.f, xx = 0.f, yy = 0.f, zz = 0.f;
        #pragma unroll
        for (int k = 0; k < WSZ; k++) {
            float g = gw.w[k];
            m1 += g * h1[r + k][c];
            m2 += g * h2[r + k][c];
            xx += g * h3[r + k][c];
            yy += g * h4[r + k][c];
            zz += g * h5[r + k][c];
        }
        const float C1 = 1e-4f;   // 0.01^2
        const float C2 = 9e-4f;   // 0.03^2
        float mu1sq = m1 * m1;
        float mu2sq = m2 * m2;
        float mu12  = m1 * m2;
        float sig1  = xx - mu1sq;
        float sig2  = yy - mu2sq;
        float sig12 = zz - mu12;
        float lum = (2.f * mu12 + C1) / (mu1sq + mu2sq + C1);
        float con = (2.f * sig12 + C2) / (sig1 + sig2 + C2);
        float str = (sig12 + C2) / (sqrtf(sig1) * sqrtf(sig2) + C2);
        localsum += lum * con * str;
    }

    // Wave-level reduce (64 lanes), then one atomic per wave.
    for (int off = 32; off > 0; off >>= 1)
        localsum += __shfl_down(localsum, off, 64);
    if ((tid & 63) == 0)
        atomicAdd(acc, (double)localsum);
}

// b2[b][p] = mean over 16 depth slices of img2
__global__ __launch_bounds__(256) void depth_mean_kernel(
    const float* __restrict__ img2, float* __restrict__ out)
{
    int idx = blockIdx.x * 256 + threadIdx.x;   // 4*SLICE threads
    int b = idx / SLICE;
    int p = idx - b * SLICE;
    const float* src = img2 + (long)b * 16 * SLICE + p;
    float s = 0.f;
    #pragma unroll
    for (int d = 0; d < 16; d++)
        s += src[(long)d * SLICE];
    out[idx] = s * (1.f / 16.f);
}

__global__ void finalize_kernel(const double* __restrict__ acc, float* __restrict__ out)
{
    double loss3 = 1.0 - acc[0] / (64.0 * (double)SLICE);
    double loss2 = 1.0 - acc[1] / (4.0 * (double)SLICE);
    out[0] = (float)(loss3 + loss2);
}

extern "C" void kernel_launch(void* const* d_in, const int* in_sizes, int n_in,
                              void* d_out, int out_size, void* d_ws, size_t ws_size,
                              hipStream_t stream)
{
    const float* img1_3d = (const float*)d_in[0];   // [4,1,16,512,512]
    const float* img1_2d = (const float*)d_in[1];   // [4,1,512,512]
    const float* img2    = (const float*)d_in[2];   // [4,1,16,512,512]
    float* out = (float*)d_out;

    double* acc = (double*)d_ws;                      // 2 accumulators
    float*  b2  = (float*)((char*)d_ws + 256);        // 4 MB depth-mean buffer

    // Gaussian weights, computed exactly like cv2.getGaussianKernel(11, 1.5):
    // double math, normalized, cast to float.
    G11 gw;
    {
        double g[WSZ], s = 0.0;
        for (int i = 0; i < WSZ; i++) {
            double x = (double)i - (WSZ - 1) / 2.0;
            g[i] = std::exp(-(x * x) / (2.0 * 1.5 * 1.5));
            s += g[i];
        }
        for (int i = 0; i < WSZ; i++) gw.w[i] = (float)(g[i] / s);
    }

    hipMemsetAsync(acc, 0, 2 * sizeof(double), stream);

    // 3D part: 64 slice pairs.
    ssim_tile_kernel<<<dim3(IMG_W / TX, IMG_H / TY, 64), 256, 0, stream>>>(
        img1_3d, img2, acc + 0, gw);

    // Depth mean of img2 -> b2.
    depth_mean_kernel<<<(4 * SLICE) / 256, 256, 0, stream>>>(img2, b2);

    // 2D part: 4 image pairs.
    ssim_tile_kernel<<<dim3(IMG_W / TX, IMG_H / TY, 4), 256, 0, stream>>>(
        img1_2d, b2, acc + 1, gw);

    finalize_kernel<<<1, 1, 0, stream>>>(acc, out);
}

// Round 2
// 186.371 us; speedup vs baseline: 4.7992x; 4.7992x over previous
//
#include <hip/hip_runtime.h>
#include <cmath>

// SSIM loss, row-sliding fused kernel.
// Block = 512 threads = one full image row width (1 thread per column).
// Iterates down a band of rows: per row, coalesced global load -> small
// double-buffered LDS row buffer -> horizontal 11-tap blur of 5 channels
// (a, b, a^2, b^2, ab) -> vertical blur via rotating 11-slot register
// accumulators (statically indexed through unroll-by-11) -> SSIM formula ->
// block reduce -> one double atomicAdd per block.

#define WSZ 11
#define IMG 512
#define SLICE (IMG * IMG)

struct G11 { float w[WSZ]; };

template<int BAND, bool MEAN16>
__global__ __launch_bounds__(512, 4)
void ssim_band_kernel(const float* __restrict__ A, const float* __restrict__ B,
                      double* __restrict__ acc, G11 gw)
{
    // steps = ceil((BAND+10)/11)*11
    constexpr int STEPS = ((BAND + 10 + 10) / 11) * 11;

    __shared__ float rbA[2][528];   // row buffers, 5-wide zero pad each side
    __shared__ float rbB[2][528];
    __shared__ float bsum[8];

    const int x  = threadIdx.x;             // column 0..511
    const int y0 = blockIdx.x * BAND;       // band start row

    const float* Ap;
    const float* Bp;
    if (MEAN16) {
        Ap = A + (long)blockIdx.y * SLICE;        // img1_2d[b]
        Bp = B + (long)blockIdx.y * 16 * SLICE;   // img2[b, 0..15]
    } else {
        Ap = A + (long)blockIdx.y * SLICE;        // slice pair
        Bp = B + (long)blockIdx.y * SLICE;
    }

    // zero the horizontal pads once
    if (x < 5) {
        rbA[0][x] = 0.f; rbA[1][x] = 0.f;
        rbB[0][x] = 0.f; rbB[1][x] = 0.f;
        rbA[0][517 + x] = 0.f; rbA[1][517 + x] = 0.f;
        rbB[0][517 + x] = 0.f; rbB[1][517 + x] = 0.f;
    }

    // rotating vertical accumulators, 11 slots x 5 channels, all static-indexed
    float aM1[11], aM2[11], aXX[11], aYY[11], aZZ[11];
    #pragma unroll
    for (int i = 0; i < 11; i++) {
        aM1[i] = 0.f; aM2[i] = 0.f; aXX[i] = 0.f; aYY[i] = 0.f; aZZ[i] = 0.f;
    }

    float sum = 0.f;

    // prefetch row for t=0 (r = y0-5)
    float aN = 0.f, bN = 0.f;
    {
        int r = y0 - 5;
        if (r >= 0 && r < IMG) {
            aN = Ap[(long)r * IMG + x];
            if (MEAN16) {
                float s = 0.f;
                #pragma unroll
                for (int d = 0; d < 16; d++)
                    s += Bp[(long)d * SLICE + r * IMG + x];
                bN = s * (1.f / 16.f);
            } else {
                bN = Bp[(long)r * IMG + x];
            }
        }
    }
    __syncthreads();   // pads visible before first tap reads

    for (int t0 = 0; t0 < STEPS; t0 += 11) {
        #pragma unroll
        for (int u = 0; u < 11; u++) {
            const int t = t0 + u;
            const int r = y0 - 5 + t;               // input row this step
            const bool rv = (r >= 0) && (r < IMG);  // block-uniform
            const int buf = t & 1;

            float h1 = 0.f, h2 = 0.f, h3 = 0.f, h4 = 0.f, h5 = 0.f;

            if (rv) {
                rbA[buf][x + 5] = aN;
                rbB[buf][x + 5] = bN;
            }

            // prefetch next row while this row's LDS write drains
            {
                int rn = r + 1;
                aN = 0.f; bN = 0.f;
                if ((t + 1 < STEPS) && rn >= 0 && rn < IMG) {
                    aN = Ap[(long)rn * IMG + x];
                    if (MEAN16) {
                        float s = 0.f;
                        #pragma unroll
                        for (int d = 0; d < 16; d++)
                            s += Bp[(long)d * SLICE + rn * IMG + x];
                        bN = s * (1.f / 16.f);
                    } else {
                        bN = Bp[(long)rn * IMG + x];
                    }
                }
            }

            if (rv) {
                __syncthreads();
                #pragma unroll
                for (int k = 0; k < WSZ; k++) {
                    float gk = gw.w[k];
                    float va = rbA[buf][x + k];
                    float vb = rbB[buf][x + k];
                    float ta = gk * va, tb = gk * vb;
                    h1 += ta;      h2 += tb;
                    h3 += ta * va; h4 += tb * vb; h5 += ta * vb;
                }
            }

            // vertical accumulate: at step t, h contributes to outputs
            // completing at steps t..t+10 with weight g[10-j]
            #pragma unroll
            for (int j = 0; j < 11; j++) {
                const int s = (u + j) % 11;          // compile-time
                const float gj = gw.w[10 - j];
                aM1[s] += gj * h1;
                aM2[s] += gj * h2;
                aXX[s] += gj * h3;
                aYY[s] += gj * h4;
                aZZ[s] += gj * h5;
            }

            // slot u completes output row o = y0 - 10 + t
            if (t >= 10 && t < BAND + 10) {
                float m1 = aM1[u], m2 = aM2[u];
                float xx = aXX[u], yy = aYY[u], zz = aZZ[u];
                float m1s = m1 * m1, m2s = m2 * m2, m12 = m1 * m2;
                float s1 = xx - m1s, s2 = yy - m2s, s12 = zz - m12;
                const float C1 = 1e-4f, C2 = 9e-4f;
                float lum = (2.f * m12 + C1) * __builtin_amdgcn_rcpf(m1s + m2s + C1);
                float con = (2.f * s12 + C2) * __builtin_amdgcn_rcpf(s1 + s2 + C2);
                float str = (s12 + C2) * __builtin_amdgcn_rcpf(
                                __builtin_amdgcn_sqrtf(s1) * __builtin_amdgcn_sqrtf(s2) + C2);
                sum += lum * con * str;
            }
            aM1[u] = 0.f; aM2[u] = 0.f; aXX[u] = 0.f; aYY[u] = 0.f; aZZ[u] = 0.f;
        }
    }

    // block reduction: wave shuffle -> LDS -> one atomic per block
    for (int off = 32; off > 0; off >>= 1)
        sum += __shfl_down(sum, off, 64);
    if ((x & 63) == 0) bsum[x >> 6] = sum;
    __syncthreads();
    if (x == 0) {
        float tot = 0.f;
        #pragma unroll
        for (int w = 0; w < 8; w++) tot += bsum[w];
        atomicAdd(acc, (double)tot);
    }
}

__global__ void finalize_kernel(const double* __restrict__ acc, float* __restrict__ out)
{
    double loss3 = 1.0 - acc[0] / (64.0 * (double)SLICE);
    double loss2 = 1.0 - acc[1] / (4.0 * (double)SLICE);
    out[0] = (float)(loss3 + loss2);
}

extern "C" void kernel_launch(void* const* d_in, const int* in_sizes, int n_in,
                              void* d_out, int out_size, void* d_ws, size_t ws_size,
                              hipStream_t stream)
{
    const float* img1_3d = (const float*)d_in[0];   // [4,1,16,512,512] -> 64 slices
    const float* img1_2d = (const float*)d_in[1];   // [4,1,512,512]
    const float* img2    = (const float*)d_in[2];   // [4,1,16,512,512]
    float* out = (float*)d_out;

    double* acc = (double*)d_ws;   // [0]=3D sum, [1]=2D sum

    // Gaussian weights, computed like cv2.getGaussianKernel(11, 1.5) in double.
    G11 gw;
    {
        double g[WSZ], s = 0.0;
        for (int i = 0; i < WSZ; i++) {
            double xx = (double)i - (WSZ - 1) / 2.0;
            g[i] = std::exp(-(xx * xx) / (2.0 * 1.5 * 1.5));
            s += g[i];
        }
        for (int i = 0; i < WSZ; i++) gw.w[i] = (float)(g[i] / s);
    }

    hipMemsetAsync(acc, 0, 2 * sizeof(double), stream);

    // 3D: 64 slice pairs, 8 bands of 64 rows -> 512 blocks, 2 blocks/CU.
    ssim_band_kernel<64, false><<<dim3(8, 64), 512, 0, stream>>>(img1_3d, img2, acc + 0, gw);

    // 2D: 4 images vs on-the-fly depth-16 mean, 64 bands of 8 rows -> 256 blocks.
    ssim_band_kernel<8, true><<<dim3(64, 4), 512, 0, stream>>>(img1_2d, img2, acc + 1, gw);

    finalize_kernel<<<1, 1, 0, stream>>>(acc, out);
}